// Round 6
// baseline (238.846 us; speedup 1.0000x reference)
//
#include <hip/hip_runtime.h>

#define T_DIM 128
#define B_DIM 2048
#define D_DIM 1024
#define KW 8
#define NCOL (B_DIM * 16)      // 32768 columns

// Per-buffer LDS layout (bytes):
//   A region [0, 32768):  [kcL<2][jh<2][mloc<512][8 f16]   (16B units)
//   X region [32768, 40960): [kcL<2][jh<2][col<128][8 f16]
#define ABYTES 32768
#define BUFB   40960
#define CHUNKS 32              // K chunks of 32 (2 kc of 16)

typedef _Float16 f16x8 __attribute__((ext_vector_type(8)));
typedef float    f32x16 __attribute__((ext_vector_type(16)));

static __device__ __forceinline__ int imax(int a, int b) { return a > b ? a : b; }
static __device__ __forceinline__ int imin(int a, int b) { return a < b ? a : b; }

__device__ __forceinline__ void gload_lds16(const void* g, void* l) {
    __builtin_amdgcn_global_load_lds(
        (const __attribute__((address_space(1))) unsigned int*)g,
        (__attribute__((address_space(3))) unsigned int*)l, 16, 0, 0);
}

// ---------------------------------------------------------------------------
// Kernel 0: W1 fp32 [m][k] -> W1g, the exact byte image global_load_lds will
// copy per (chunk, mt) slab:  W1g[c][mt][kcL][jh][mloc][8 f16]
//   element = W1[mt*512 + mloc][c*32 + kcL*16 + jh*8 + j]
// ---------------------------------------------------------------------------
__global__ void k_cvt_w1(const float* __restrict__ W1, _Float16* __restrict__ W1g) {
    int i = blockIdx.x * 256 + threadIdx.x;   // 32768 threads
    int m = i >> 5;            // 0..1023
    int c = i & 31;            // chunk
    int mt = m >> 9, mloc = m & 511;
    const float* src = W1 + (size_t)m * D_DIM + c * 32;
    size_t base = (size_t)(c * 2 + mt) * 16384 + mloc * 8;   // f16 elems
#pragma unroll
    for (int kcL = 0; kcL < 2; ++kcL) {
#pragma unroll
        for (int jh = 0; jh < 2; ++jh) {
            float4 x0 = *(const float4*)(src + kcL * 16 + jh * 8);
            float4 x1 = *(const float4*)(src + kcL * 16 + jh * 8 + 4);
            f16x8 h;
            h[0] = (_Float16)x0.x; h[1] = (_Float16)x0.y;
            h[2] = (_Float16)x0.z; h[3] = (_Float16)x0.w;
            h[4] = (_Float16)x1.x; h[5] = (_Float16)x1.y;
            h[6] = (_Float16)x1.z; h[7] = (_Float16)x1.w;
            *(f16x8*)(W1g + base + kcL * 8192 + jh * 4096) = h;
        }
    }
}

// ---------------------------------------------------------------------------
// Kernel 1 (fused gather + GEMM + tanh/W2 epilogue):
// block = 512 m x 128 cols, 8 waves (mg<4, ng<2), wave-tile 128m x 64n.
// A staged per chunk via global_load_lds (dbuf); X reg-staged fp32->f16.
// grid = 512 blocks: bid -> mt = bid&1 (m half), cg = bid>>1 (col group).
// Writes s_part[mt][col] = partial sum over 512 m of W2[m]*tanh(.).
// ---------------------------------------------------------------------------
__launch_bounds__(512, 2)
__global__ void k_gemm(const float* __restrict__ hctx,
                       const int*   __restrict__ offsets,
                       const int*   __restrict__ stc,
                       const int*   __restrict__ sep_l,
                       const _Float16* __restrict__ W1g,
                       const float* __restrict__ W2,
                       float* __restrict__ s_part /* [2][NCOL] */) {
    __shared__ __align__(16) char lds[2 * BUFB];
    __shared__ float red[8][64];

    int bid = blockIdx.x;
    int mt  = bid & 1;
    int cg  = bid >> 1;
    int tid = threadIdx.x;
    int wid = tid >> 6;
    int lane = tid & 63;
    int lr = lane & 31;
    int hi = lane >> 5;
    int mg = wid >> 1;
    int ng = wid & 1;

    // ---- X staging setup: thread owns (s_kcL, s_jh, s_col) ----
    int s_kcL = (tid >> 8) & 1;
    int s_jh  = (tid >> 7) & 1;
    int s_col = tid & 127;
    {
    }
    int col = cg * 128 + s_col;
    int b   = col >> 4;
    int li  = col & 15;
    int off = offsets[b];
    int sep = sep_l[b];
    int st  = stc[b];
    bool in1 = (off <= sep);
    int start = in1 ? imax(off - KW, 0)   : imax(off - KW, sep + 1);
    int end   = in1 ? imin(off + KW, sep) : imin(off + KW, st);
    int idx = start + li;
    bool valid = (idx < end);
    int tc = imin(imax(idx, 0), T_DIM - 1);
    const float* sbase = hctx + ((size_t)tc * B_DIM + b) * D_DIM + s_kcL * 16 + s_jh * 8;
    int s_woff = ABYTES + ((s_kcL * 2 + s_jh) * 128 + s_col) * 16;

    // ---- A staging: wave wid copies 4KB of the 32KB slab ----
    const char* wg_bytes = (const char*)W1g;
    int a_off = wid * 4096;            // + i*1024, lane*16 added to source

    // ---- frag read offsets ----
    int a_roff = hi * 8192 + (mg * 128 + lr) * 16;          // + kcL*16384 + f*512
    int x_roff = ABYTES + (ng * 64 + lr) * 16;              // + (kcL*2+hi)*2048 + nf*512

    f32x16 acc[4][2];
#pragma unroll
    for (int f = 0; f < 4; ++f)
#pragma unroll
        for (int nf = 0; nf < 2; ++nf)
#pragma unroll
            for (int i = 0; i < 16; ++i) acc[f][nf][i] = 0.f;

    // ---- prologue: stage chunk 0 into buf0 ----
    {
        size_t slab = (size_t)(0 * 2 + mt) * 32768;
#pragma unroll
        for (int i = 0; i < 4; ++i)
            gload_lds16(wg_bytes + slab + a_off + i * 1024 + lane * 16,
                        lds + a_off + i * 1024);
        float4 z = {0.f, 0.f, 0.f, 0.f};
        float4 xa = valid ? *(const float4*)(sbase) : z;
        float4 xb = valid ? *(const float4*)(sbase + 4) : z;
        f16x8 h;
        h[0] = (_Float16)xa.x; h[1] = (_Float16)xa.y;
        h[2] = (_Float16)xa.z; h[3] = (_Float16)xa.w;
        h[4] = (_Float16)xb.x; h[5] = (_Float16)xb.y;
        h[6] = (_Float16)xb.z; h[7] = (_Float16)xb.w;
        *(f16x8*)(lds + s_woff) = h;
    }
    __syncthreads();

    // ---- main loop ----
    for (int c = 0; c < CHUNKS; ++c) {
        int cur = (c & 1) * BUFB;
        int nxt = cur ^ BUFB;

        float4 xa, xb;
        if (c < CHUNKS - 1) {
            // stage A(c+1) directly to LDS (async), X(c+1) to regs
            size_t slab = (size_t)((c + 1) * 2 + mt) * 32768;
#pragma unroll
            for (int i = 0; i < 4; ++i)
                gload_lds16(wg_bytes + slab + a_off + i * 1024 + lane * 16,
                            lds + nxt + a_off + i * 1024);
            float4 z = {0.f, 0.f, 0.f, 0.f};
            const float* sp = sbase + (c + 1) * 32;
            xa = valid ? *(const float4*)(sp) : z;
            xb = valid ? *(const float4*)(sp + 4) : z;
        }

        // read all frags for this chunk, then MFMA
        f16x8 a[2][4], x[2][2];
#pragma unroll
        for (int kcL = 0; kcL < 2; ++kcL) {
#pragma unroll
            for (int f = 0; f < 4; ++f)
                a[kcL][f] = *(const f16x8*)(lds + cur + kcL * 16384 + a_roff + f * 512);
#pragma unroll
            for (int nf = 0; nf < 2; ++nf)
                x[kcL][nf] = *(const f16x8*)(lds + cur + x_roff + (kcL * 2 + hi) * 2048 + nf * 512);
        }
#pragma unroll
        for (int kcL = 0; kcL < 2; ++kcL) {
#pragma unroll
            for (int f = 0; f < 4; ++f)
                acc[f][0] = __builtin_amdgcn_mfma_f32_32x32x16_f16(
                    a[kcL][f], x[kcL][0], acc[f][0], 0, 0, 0);
#pragma unroll
            for (int f = 0; f < 4; ++f)
                acc[f][1] = __builtin_amdgcn_mfma_f32_32x32x16_f16(
                    a[kcL][f], x[kcL][1], acc[f][1], 0, 0, 0);
        }

        if (c < CHUNKS - 1) {
            f16x8 h;
            h[0] = (_Float16)xa.x; h[1] = (_Float16)xa.y;
            h[2] = (_Float16)xa.z; h[3] = (_Float16)xa.w;
            h[4] = (_Float16)xb.x; h[5] = (_Float16)xb.y;
            h[6] = (_Float16)xb.z; h[7] = (_Float16)xb.w;
            *(f16x8*)(lds + nxt + s_woff) = h;
        }
        __syncthreads();
    }

    // ---- epilogue: tanh + W2 dot ----
    // D layout (32x32): col = lane&31, row = (r&3) + 8*(r>>2) + 4*(lane>>5)
    float sp0 = 0.f, sp1 = 0.f;
#pragma unroll
    for (int f = 0; f < 4; ++f) {
#pragma unroll
        for (int rg = 0; rg < 4; ++rg) {
            int mbase = mt * 512 + mg * 128 + f * 32 + rg * 8 + hi * 4;
            float4 w2v = *(const float4*)(W2 + mbase);
            float w2a[4] = {w2v.x, w2v.y, w2v.z, w2v.w};
#pragma unroll
            for (int j = 0; j < 4; ++j) {
                float w2 = w2a[j];
                {
                    float xv = acc[f][0][rg * 4 + j];
                    float e = __expf(2.f * xv);
                    sp0 += w2 * (1.f - 2.f / (e + 1.f));
                }
                {
                    float xv = acc[f][1][rg * 4 + j];
                    float e = __expf(2.f * xv);
                    sp1 += w2 * (1.f - 2.f / (e + 1.f));
                }
            }
        }
    }
    sp0 += __shfl_xor(sp0, 32, 64);   // combine hi halves (same col)
    sp1 += __shfl_xor(sp1, 32, 64);

    if (hi == 0) {
        red[wid][lr]      = sp0;      // col-local ng*64 + lr
        red[wid][32 + lr] = sp1;      // col-local ng*64 + 32 + lr
    }
    __syncthreads();
    if (tid < 128) {
        int ngc = tid >> 6;           // which ng owns this col
        int cl  = tid & 63;
        float s = 0.f;
#pragma unroll
        for (int mgi = 0; mgi < 4; ++mgi) s += red[mgi * 2 + ngc][cl];
        s_part[(size_t)mt * NCOL + cg * 128 + tid] = s;
    }
}

// ---------------------------------------------------------------------------
// Kernel 2: sum mt-partials, per-l max and sum-exp over B (softmax stats).
// ---------------------------------------------------------------------------
__global__ void k_smax1(const float* __restrict__ s_part,
                        float* __restrict__ s_raw,
                        float* __restrict__ lstats /* [32]: 16 max, 16 sum */) {
    int l = blockIdx.x;
    int t = threadIdx.x;
    int lane = t & 63, wid = t >> 6;

    float v[8];
    float mx = -__builtin_inff();
#pragma unroll
    for (int i = 0; i < 8; ++i) {
        int b = i * 256 + t;
        float x = s_part[b * 16 + l] + s_part[NCOL + b * 16 + l];
        v[i] = x;
        s_raw[b * 16 + l] = x;
        mx = fmaxf(mx, x);
    }
#pragma unroll
    for (int d = 1; d < 64; d <<= 1) mx = fmaxf(mx, __shfl_xor(mx, d, 64));
    __shared__ float rm[4];
    if (lane == 0) rm[wid] = mx;
    __syncthreads();
    mx = fmaxf(fmaxf(rm[0], rm[1]), fmaxf(rm[2], rm[3]));

    float se = 0.f;
#pragma unroll
    for (int i = 0; i < 8; ++i) se += __expf(v[i] - mx);
#pragma unroll
    for (int d = 1; d < 64; d <<= 1) se += __shfl_xor(se, d, 64);
    __shared__ float rs[4];
    if (lane == 0) rs[wid] = se;
    __syncthreads();
    if (t == 0) {
        lstats[l]      = mx;
        lstats[16 + l] = rs[0] + rs[1] + rs[2] + rs[3];
    }
}

// ---------------------------------------------------------------------------
// Kernel 3: masked softmax over l + weighted gather-sum to output.
// ---------------------------------------------------------------------------
__global__ void k_out(const float* __restrict__ hctx,
                      const int*   __restrict__ offsets,
                      const int*   __restrict__ stc,
                      const int*   __restrict__ sep_l,
                      const float* __restrict__ s_raw,
                      const float* __restrict__ lstats,
                      float* __restrict__ out) {
    int b = blockIdx.x;
    int t = threadIdx.x;

    int off = offsets[b];
    int sep = sep_l[b];
    int st  = stc[b];
    bool in1 = (off <= sep);
    int start = in1 ? imax(off - KW, 0)   : imax(off - KW, sep + 1);
    int end   = in1 ? imin(off + KW, sep) : imin(off + KW, st);

    float p[16];
    float m2 = -__builtin_inff();
#pragma unroll
    for (int l = 0; l < 16; ++l) {
        bool valid = (start + l) < end;
        float s = s_raw[b * 16 + l];
        float pl = __expf(s - lstats[l]) / lstats[16 + l];
        p[l] = valid ? pl : -__builtin_inff();
        m2 = fmaxf(m2, p[l]);
    }
    float q[16];
    float qs = 0.f;
#pragma unroll
    for (int l = 0; l < 16; ++l) {
        float e = __expf(p[l] - m2);   // exp(-inf) = 0 for invalid
        q[l] = e;
        qs += e;
    }
    float rqs = 1.f / qs;

    float4 acc = {0.f, 0.f, 0.f, 0.f};
#pragma unroll
    for (int l = 0; l < 16; ++l) {
        float wl = q[l] * rqs;
        if (wl > 0.f) {
            int tr = imin(imax(start + l, 0), T_DIM - 1);
            float4 x = *((const float4*)(hctx + ((size_t)tr * B_DIM + b) * D_DIM) + t);
            acc.x += wl * x.x; acc.y += wl * x.y;
            acc.z += wl * x.z; acc.w += wl * x.w;
        }
    }
    *((float4*)(out + (size_t)b * D_DIM) + t) = acc;
}

// ---------------------------------------------------------------------------
extern "C" void kernel_launch(void* const* d_in, const int* in_sizes, int n_in,
                              void* d_out, int out_size, void* d_ws, size_t ws_size,
                              hipStream_t stream) {
    const float* hctx    = (const float*)d_in[0];
    const int*   offsets = (const int*)d_in[1];
    const int*   stc     = (const int*)d_in[2];
    const int*   sep     = (const int*)d_in[3];
    // d_in[4] = no_local (unused by reference)
    const float* W1      = (const float*)d_in[5];
    const float* W2      = (const float*)d_in[6];
    float* out = (float*)d_out;

    char* ws = (char*)d_ws;
    _Float16* W1g    = (_Float16*)ws;                          // 2 MB
    float*    s_part = (float*)(ws + (2u << 20));              // 256 KB
    float*    s_raw  = (float*)(ws + (2u << 20) + (256u << 10));   // 128 KB
    float*    lstats = (float*)(ws + (2u << 20) + (384u << 10));

    hipLaunchKernelGGL(k_cvt_w1, dim3(128),  dim3(256), 0, stream, W1, W1g);
    hipLaunchKernelGGL(k_gemm,   dim3(512),  dim3(512), 0, stream,
                       hctx, offsets, stc, sep, W1g, W2, s_part);
    hipLaunchKernelGGL(k_smax1,  dim3(16),   dim3(256), 0, stream,
                       s_part, s_raw, lstats);
    hipLaunchKernelGGL(k_out,    dim3(2048), dim3(256), 0, stream,
                       hctx, offsets, stc, sep, s_raw, lstats, out);
}

// Round 7
// 187.673 us; speedup vs baseline: 1.2727x; 1.2727x over previous
//
#include <hip/hip_runtime.h>

#define T_DIM 128
#define B_DIM 2048
#define D_DIM 1024
#define KW 8
#define NCOL (B_DIM * 16)      // 32768 columns

// X LDS buffer: [kcL<8][jh<2][col<128][8 f16] = 32768 B per buffer
#define XBUF 32768

typedef _Float16 f16x8 __attribute__((ext_vector_type(8)));
typedef float    f32x16 __attribute__((ext_vector_type(16)));

static __device__ __forceinline__ int imax(int a, int b) { return a > b ? a : b; }
static __device__ __forceinline__ int imin(int a, int b) { return a < b ? a : b; }

// ---------------------------------------------------------------------------
// Kernel 0: W1 fp32 [m][k] -> fp16 fragment-interleaved W1f[kc][m][j]
//   W1f[(kc*1024 + m)*16 + j] = W1[m*1024 + kc*16 + j],  kc<64, j<16
// ---------------------------------------------------------------------------
__global__ void k_cvt_w1(const float* __restrict__ W1, _Float16* __restrict__ W1f) {
    int i  = blockIdx.x * 256 + threadIdx.x;   // 65536 threads
    int m  = i >> 6;
    int kc = i & 63;
    const float* src = W1 + (size_t)m * D_DIM + kc * 16;
    float4 x0 = *(const float4*)(src);
    float4 x1 = *(const float4*)(src + 4);
    float4 x2 = *(const float4*)(src + 8);
    float4 x3 = *(const float4*)(src + 12);
    f16x8 h0, h1;
    h0[0] = (_Float16)x0.x; h0[1] = (_Float16)x0.y;
    h0[2] = (_Float16)x0.z; h0[3] = (_Float16)x0.w;
    h0[4] = (_Float16)x1.x; h0[5] = (_Float16)x1.y;
    h0[6] = (_Float16)x1.z; h0[7] = (_Float16)x1.w;
    h1[0] = (_Float16)x2.x; h1[1] = (_Float16)x2.y;
    h1[2] = (_Float16)x2.z; h1[3] = (_Float16)x2.w;
    h1[4] = (_Float16)x3.x; h1[5] = (_Float16)x3.y;
    h1[6] = (_Float16)x3.z; h1[7] = (_Float16)x3.w;
    _Float16* dst = W1f + ((size_t)kc * 1024 + m) * 16;
    *(f16x8*)(dst)     = h0;
    *(f16x8*)(dst + 8) = h1;
}

// ---------------------------------------------------------------------------
// Kernel 1 (fused gather + GEMM + tanh/W2 epilogue):
// block = 512 m x 128 cols, 8 waves (mg<4 x ng<2), wave-tile 128m x 64n,
// acc[4][2]. A streamed from L2-resident W1f (ng-pairs share -> L1 dedup);
// X gathered fp32 -> f16 staged in LDS (dbuf, 8 chunks of BK=128).
// grid = 512: bid -> mt = bid&1 (m half), cg = bid>>1 (128-col group).
// Writes s_part[mt][col] = sum over 512 m of W2[m]*tanh(dot).
// ---------------------------------------------------------------------------
__launch_bounds__(512, 2)
__global__ void k_gemm(const float* __restrict__ hctx,
                       const int*   __restrict__ offsets,
                       const int*   __restrict__ stc,
                       const int*   __restrict__ sep_l,
                       const _Float16* __restrict__ W1f,
                       const float* __restrict__ W2,
                       float* __restrict__ s_part /* [2][NCOL] */) {
    __shared__ __align__(16) char ldsx[2 * XBUF];
    __shared__ float red[8][64];

    int bid = blockIdx.x;
    int mt  = bid & 1;
    int cg  = bid >> 1;
    int tid = threadIdx.x;
    int wid = tid >> 6;
    int lane = tid & 63;
    int lr = lane & 31;
    int hi = lane >> 5;
    int mg = wid >> 1;
    int ng = wid & 1;

    // ---- X staging: thread owns col = tid&127, k-span ks*32..+31 per chunk ----
    int s_col = tid & 127;
    int ks    = tid >> 7;           // 0..3
    int col = cg * 128 + s_col;
    int b   = col >> 4;
    int li  = col & 15;
    int off = offsets[b];
    int sep = sep_l[b];
    int st  = stc[b];
    bool in1 = (off <= sep);
    int start = in1 ? imax(off - KW, 0)   : imax(off - KW, sep + 1);
    int end   = in1 ? imin(off + KW, sep) : imin(off + KW, st);
    int idx = start + li;
    bool valid = (idx < end);
    int tc = imin(imax(idx, 0), T_DIM - 1);
    const float* sbase = hctx + ((size_t)tc * B_DIM + b) * D_DIM + ks * 32;
    // writes 4 x f16x8 at (ks*2+p)*4096 + jh*2048 + s_col*16
    int s_woff = ks * 8192 + s_col * 16;

    // ---- A geometry: frag (f, kc) at ap + kc*16384 + f*512 ----
    const _Float16* ap = W1f + (size_t)(mt * 512 + mg * 128 + lr) * 16 + hi * 8;

    // ---- X frag read: (kcL, nf) at kcL*4096 + x_roff + nf*512 ----
    int x_roff = hi * 2048 + (ng * 64 + lr) * 16;

    f32x16 acc[4][2];
#pragma unroll
    for (int f = 0; f < 4; ++f)
#pragma unroll
        for (int nf = 0; nf < 2; ++nf)
#pragma unroll
            for (int i = 0; i < 16; ++i) acc[f][nf][i] = 0.f;

    // ---- prologue: stage chunk 0 into buf0 ----
    {
        float4 xv[8];
        float4 z = {0.f, 0.f, 0.f, 0.f};
#pragma unroll
        for (int q = 0; q < 8; ++q)
            xv[q] = valid ? *(const float4*)(sbase + q * 4) : z;
#pragma unroll
        for (int p = 0; p < 2; ++p)
#pragma unroll
            for (int jh = 0; jh < 2; ++jh) {
                float4 u = xv[p * 4 + jh * 2], v = xv[p * 4 + jh * 2 + 1];
                f16x8 h;
                h[0] = (_Float16)u.x; h[1] = (_Float16)u.y;
                h[2] = (_Float16)u.z; h[3] = (_Float16)u.w;
                h[4] = (_Float16)v.x; h[5] = (_Float16)v.y;
                h[6] = (_Float16)v.z; h[7] = (_Float16)v.w;
                *(f16x8*)(ldsx + s_woff + p * 4096 + jh * 2048) = h;
            }
    }
    __syncthreads();

    // ---- main loop: 8 chunks of 128 k ----
    for (int c = 0; c < 8; ++c) {
        int cur = (c & 1) * XBUF;

        float4 xn[8];
        if (c < 7) {
            float4 z = {0.f, 0.f, 0.f, 0.f};
            const float* sp = sbase + (c + 1) * 128;
#pragma unroll
            for (int q = 0; q < 8; ++q)
                xn[q] = valid ? *(const float4*)(sp + q * 4) : z;
        }

#pragma unroll
        for (int kcL = 0; kcL < 8; ++kcL) {
            int kc = c * 8 + kcL;
            f16x8 a[4];
#pragma unroll
            for (int f = 0; f < 4; ++f)
                a[f] = *(const f16x8*)(ap + (size_t)kc * 16384 + f * 512);
            f16x8 x0 = *(const f16x8*)(ldsx + cur + kcL * 4096 + x_roff);
            f16x8 x1 = *(const f16x8*)(ldsx + cur + kcL * 4096 + x_roff + 512);
#pragma unroll
            for (int f = 0; f < 4; ++f)
                acc[f][0] = __builtin_amdgcn_mfma_f32_32x32x16_f16(
                    a[f], x0, acc[f][0], 0, 0, 0);
#pragma unroll
            for (int f = 0; f < 4; ++f)
                acc[f][1] = __builtin_amdgcn_mfma_f32_32x32x16_f16(
                    a[f], x1, acc[f][1], 0, 0, 0);
        }

        if (c < 7) {
            int nxt = ((c + 1) & 1) * XBUF;
#pragma unroll
            for (int p = 0; p < 2; ++p)
#pragma unroll
                for (int jh = 0; jh < 2; ++jh) {
                    float4 u = xn[p * 4 + jh * 2], v = xn[p * 4 + jh * 2 + 1];
                    f16x8 h;
                    h[0] = (_Float16)u.x; h[1] = (_Float16)u.y;
                    h[2] = (_Float16)u.z; h[3] = (_Float16)u.w;
                    h[4] = (_Float16)v.x; h[5] = (_Float16)v.y;
                    h[6] = (_Float16)v.z; h[7] = (_Float16)v.w;
                    *(f16x8*)(ldsx + nxt + s_woff + p * 4096 + jh * 2048) = h;
                }
        }
        __syncthreads();
    }

    // ---- epilogue: tanh + W2 dot ----
    // D layout (32x32): col = lane&31, row = (r&3) + 8*(r>>2) + 4*(lane>>5)
    float sp0 = 0.f, sp1 = 0.f;
#pragma unroll
    for (int f = 0; f < 4; ++f) {
#pragma unroll
        for (int rg = 0; rg < 4; ++rg) {
            int mbase = mt * 512 + mg * 128 + f * 32 + rg * 8 + hi * 4;
            float4 w2v = *(const float4*)(W2 + mbase);
            float w2a[4] = {w2v.x, w2v.y, w2v.z, w2v.w};
#pragma unroll
            for (int j = 0; j < 4; ++j) {
                float w2 = w2a[j];
                {
                    float xv = acc[f][0][rg * 4 + j];
                    float e = __expf(2.f * xv);
                    sp0 += w2 * (1.f - 2.f / (e + 1.f));
                }
                {
                    float xv = acc[f][1][rg * 4 + j];
                    float e = __expf(2.f * xv);
                    sp1 += w2 * (1.f - 2.f / (e + 1.f));
                }
            }
        }
    }
    sp0 += __shfl_xor(sp0, 32, 64);   // fold hi halves (same col)
    sp1 += __shfl_xor(sp1, 32, 64);

    if (hi == 0) {
        red[wid][lr]      = sp0;      // col-local = ng*64 + lr
        red[wid][32 + lr] = sp1;      // col-local = ng*64 + 32 + lr
    }
    __syncthreads();
    if (tid < 128) {
        int ngc = tid >> 6;           // ng owning this col
        int cl  = tid & 63;
        float s = 0.f;
#pragma unroll
        for (int mgi = 0; mgi < 4; ++mgi) s += red[mgi * 2 + ngc][cl];
        s_part[(size_t)mt * NCOL + cg * 128 + tid] = s;
    }
}

// ---------------------------------------------------------------------------
// Kernel 2: sum mt-partials, per-l max and sum-exp over B (softmax stats).
// ---------------------------------------------------------------------------
__global__ void k_smax1(const float* __restrict__ s_part,
                        float* __restrict__ s_raw,
                        float* __restrict__ lstats /* [32]: 16 max, 16 sum */) {
    int l = blockIdx.x;
    int t = threadIdx.x;
    int lane = t & 63, wid = t >> 6;

    float v[8];
    float mx = -__builtin_inff();
#pragma unroll
    for (int i = 0; i < 8; ++i) {
        int b = i * 256 + t;
        float x = s_part[b * 16 + l] + s_part[NCOL + b * 16 + l];
        v[i] = x;
        s_raw[b * 16 + l] = x;
        mx = fmaxf(mx, x);
    }
#pragma unroll
    for (int d = 1; d < 64; d <<= 1) mx = fmaxf(mx, __shfl_xor(mx, d, 64));
    __shared__ float rm[4];
    if (lane == 0) rm[wid] = mx;
    __syncthreads();
    mx = fmaxf(fmaxf(rm[0], rm[1]), fmaxf(rm[2], rm[3]));

    float se = 0.f;
#pragma unroll
    for (int i = 0; i < 8; ++i) se += __expf(v[i] - mx);
#pragma unroll
    for (int d = 1; d < 64; d <<= 1) se += __shfl_xor(se, d, 64);
    __shared__ float rs[4];
    if (lane == 0) rs[wid] = se;
    __syncthreads();
    if (t == 0) {
        lstats[l]      = mx;
        lstats[16 + l] = rs[0] + rs[1] + rs[2] + rs[3];
    }
}

// ---------------------------------------------------------------------------
// Kernel 3: masked softmax over l + weighted gather-sum to output.
// ---------------------------------------------------------------------------
__global__ void k_out(const float* __restrict__ hctx,
                      const int*   __restrict__ offsets,
                      const int*   __restrict__ stc,
                      const int*   __restrict__ sep_l,
                      const float* __restrict__ s_raw,
                      const float* __restrict__ lstats,
                      float* __restrict__ out) {
    int b = blockIdx.x;
    int t = threadIdx.x;

    int off = offsets[b];
    int sep = sep_l[b];
    int st  = stc[b];
    bool in1 = (off <= sep);
    int start = in1 ? imax(off - KW, 0)   : imax(off - KW, sep + 1);
    int end   = in1 ? imin(off + KW, sep) : imin(off + KW, st);

    float p[16];
    float m2 = -__builtin_inff();
#pragma unroll
    for (int l = 0; l < 16; ++l) {
        bool valid = (start + l) < end;
        float s = s_raw[b * 16 + l];
        float pl = __expf(s - lstats[l]) / lstats[16 + l];
        p[l] = valid ? pl : -__builtin_inff();
        m2 = fmaxf(m2, p[l]);
    }
    float q[16];
    float qs = 0.f;
#pragma unroll
    for (int l = 0; l < 16; ++l) {
        float e = __expf(p[l] - m2);   // exp(-inf) = 0 for invalid
        q[l] = e;
        qs += e;
    }
    float rqs = 1.f / qs;

    float4 acc = {0.f, 0.f, 0.f, 0.f};
#pragma unroll
    for (int l = 0; l < 16; ++l) {
        float wl = q[l] * rqs;
        if (wl > 0.f) {
            int tr = imin(imax(start + l, 0), T_DIM - 1);
            float4 x = *((const float4*)(hctx + ((size_t)tr * B_DIM + b) * D_DIM) + t);
            acc.x += wl * x.x; acc.y += wl * x.y;
            acc.z += wl * x.z; acc.w += wl * x.w;
        }
    }
    *((float4*)(out + (size_t)b * D_DIM) + t) = acc;
}

// ---------------------------------------------------------------------------
extern "C" void kernel_launch(void* const* d_in, const int* in_sizes, int n_in,
                              void* d_out, int out_size, void* d_ws, size_t ws_size,
                              hipStream_t stream) {
    const float* hctx    = (const float*)d_in[0];
    const int*   offsets = (const int*)d_in[1];
    const int*   stc     = (const int*)d_in[2];
    const int*   sep     = (const int*)d_in[3];
    // d_in[4] = no_local (unused by reference)
    const float* W1      = (const float*)d_in[5];
    const float* W2      = (const float*)d_in[6];
    float* out = (float*)d_out;

    char* ws = (char*)d_ws;
    _Float16* W1f    = (_Float16*)ws;                              // 2 MB
    float*    s_part = (float*)(ws + (2u << 20));                  // 256 KB
    float*    s_raw  = (float*)(ws + (2u << 20) + (256u << 10));   // 128 KB
    float*    lstats = (float*)(ws + (2u << 20) + (384u << 10));

    hipLaunchKernelGGL(k_cvt_w1, dim3(256),  dim3(256), 0, stream, W1, W1f);
    hipLaunchKernelGGL(k_gemm,   dim3(512),  dim3(512), 0, stream,
                       hctx, offsets, stc, sep, W1f, W2, s_part);
    hipLaunchKernelGGL(k_smax1,  dim3(16),   dim3(256), 0, stream,
                       s_part, s_raw, lstats);
    hipLaunchKernelGGL(k_out,    dim3(2048), dim3(256), 0, stream,
                       hctx, offsets, stc, sep, s_raw, lstats, out);
}